// Round 7
// baseline (226.485 us; speedup 1.0000x reference)
//
#include <hip/hip_runtime.h>

// BlockSample: out[(b*H+y)*W+x, ch, i, j] = in[b, ch, y+i-3, x+j-2] (zero pad),
// taps (i==3, j>=2) masked to zero.
//
// R1: scattered reads -> TA-bound 150 us. R4/R5: LDS staging + 1KB/wave
// coalesced float4 stores -> ~67 us. R6: YT=3 y-tiling -> ~52 us.
// R7: YT=6 (stage 9 rows x 16 ch, 31.7 KB LDS). Grid 768 = 3 blocks/CU
// (12 waves); fill overhead per output byte halves again; 96 blocks/XCD =
// exactly one batch image per XCD -> 1.77 MB input working set fully
// L2-resident per XCD. PITCH stays 55 (odd): store-phase reads <=3-way bank
// aliased; PITCH=56 would give 16-way conflicts (checked, rejected).

#define BB 8
#define CC 192
#define HH 48
#define WW 48
#define G   16                 // channels per block
#define NCHG (CC / G)          // 12
#define YT  6                  // y's per block
#define NYG (HH / YT)          // 8
#define NROW (YT + 3)          // 9 staged rows per channel
#define PITCH 55               // 3 left pad + 48 + 4 spare; odd -> low conflicts
#define NBLK (BB * NCHG * NYG) // 768 blocks = 3/CU exactly
#define NXCD 8

typedef float vfloat4 __attribute__((ext_vector_type(4)));

__global__ __launch_bounds__(256) void
blocksample_kernel(const float* __restrict__ in, float* __restrict__ out) {
    // XCD swizzle: 96 consecutive g per XCD = one full batch image b per XCD
    // -> all input + halo re-reads are local-L2 hits.
    const int id  = blockIdx.x;
    const int xcd = id & (NXCD - 1);
    const int g   = xcd * (NBLK / NXCD) + (id >> 3);

    const int yg  = g % NYG;
    const int chg = (g / NYG) % NCHG;
    const int b   = g / (NYG * NCHG);
    const int y0  = yg * YT;

    __shared__ float lds[G * NROW * PITCH];       // 16 x 9 x 55 x 4B = 31,680 B

    const int t = threadIdx.x;

    // 1) zero the read halo: cols {1,2,51} of each of the 144 rows (432 words).
    for (int k = t; k < G * NROW * 3; k += 256) {
        const int rc = k / 3;
        const int m  = k - rc * 3;
        const int c  = (m == 0) ? 1 : ((m == 1) ? 2 : 51);
        lds[rc * PITCH + c] = 0.0f;
    }

    // 2) fill interior with float4 loads: rc = ch*NROW + dyr covers rows
    //    y0-3 .. y0+YT-1 per channel; OOB rows (top edge only) -> zeros.
    const float* inb = in + ((size_t)(b * CC + chg * G) * HH) * WW;
    for (int f = t; f < G * NROW * (WW / 4); f += 256) {
        const int rc  = f / (WW / 4);             // 0..143
        const int c4  = f - rc * (WW / 4);        // 0..11
        const int ch  = rc / NROW;
        const int dyr = rc - ch * NROW;
        const int row = y0 - 3 + dyr;
        vfloat4 val = (vfloat4)(0.0f);
        if (row >= 0 && row < HH)
            val = *(const vfloat4*)(inb + ((size_t)(ch * HH + row)) * WW + c4 * 4);
        float* dst = lds + rc * PITCH + 3 + c4 * 4;
        dst[0] = val.x; dst[1] = val.y; dst[2] = val.z; dst[3] = val.w;
    }
    __syncthreads();

    // 3) stores: lane l -> (ch = l>>2, i = l&3); wave w covers x = w, w+4, ...
    //    LDS row = ch*NROW + dy + i; out float4 = pix*768 + chg*64 + l;
    //    per-pixel stride 768, per-y stride WW*768 float4.
    const int w  = t >> 6;
    const int l  = t & 63;
    const int i  = l & 3;
    const int ch = l >> 2;
    const float* lbase = lds + (ch * NROW + i) * PITCH;

    vfloat4* outb = (vfloat4*)out
        + ((size_t)((b * HH + y0) * WW) * CC + chg * G) * 4 + l;

    for (int dy = 0; dy < YT; ++dy) {
        const float* p = lbase + dy * PITCH + (w + 1);   // LDS col x+1 at x=w
        vfloat4* op = outb + (size_t)dy * (WW * CC * 4) + (size_t)w * (CC * 4);
        for (int xi = 0; xi < WW / 4; ++xi) {
            vfloat4 v;
            v.x = p[0];
            v.y = p[1];
            v.z = p[2];
            v.w = p[3];
            if (i == 3) { v.z = 0.0f; v.w = 0.0f; }      // masked taps (3,2),(3,3)
            *op = v;
            p  += 4;                                      // x += 4
            op += 4 * (CC * 4);
        }
    }
}

extern "C" void kernel_launch(void* const* d_in, const int* in_sizes, int n_in,
                              void* d_out, int out_size, void* d_ws, size_t ws_size,
                              hipStream_t stream) {
    const float* in = (const float*)d_in[0];
    float* out = (float*)d_out;
    blocksample_kernel<<<dim3(NBLK), dim3(256), 0, stream>>>(in, out);
}